// Round 17
// baseline (113.520 us; speedup 1.0000x reference)
//
#include <hip/hip_runtime.h>
#include <hip/hip_bf16.h>

typedef __attribute__((ext_vector_type(8))) short short8;
typedef __attribute__((ext_vector_type(16))) float float16v;

// Workspace layout (bytes):
//   xTg  bf16 [16 b][32 g][34 h][34 w][8 c]             : 9,469,952
//   Wg   bf16 [9 s][4 pair][4 nq][8 g][64 n][8 c]       : 1,179,648
//   biasout f32 [256]                                   : 1,024
#define XT_BYTES (16*32*34*34*8*2)
#define WG_BYTES (9*4*4*8*64*8*2)

// ---------------------------------------------------------------------------
// k_prep = R28 (best): transpose + conflict-free register-butterfly build_w.
// ---------------------------------------------------------------------------
__global__ __launch_bounds__(256) void k_prep(const float* __restrict__ x,
                                              const float* __restrict__ tw1,
                                              const float* __restrict__ tw2,
                                              const float* __restrict__ bias,
                                              __hip_bfloat16* __restrict__ xTg,
                                              __hip_bfloat16* __restrict__ Wg,
                                              float* __restrict__ biasout) {
  __shared__ __align__(16) char smem[256 * 33 * 4];   // 33792 B
  int blk = blockIdx.x;
  int tid = threadIdx.x;

  if (blk < 512) {   // ---------------- transpose ----------------
    float* tile = (float*)smem;
    char* xTB = (char*)xTg;
    int h = blk & 31, b = blk >> 5;
    {
      int w4 = (tid & 7) * 4, c0 = tid >> 3;
#pragma unroll
      for (int j = 0; j < 8; ++j) {
        int ci = c0 + 32 * j;
        float4 v = *(const float4*)&x[((b * 256 + ci) * 32 + h) * 32 + w4];
        *(float4*)&tile[ci * 33 + w4] = v;
      }
    }
    __syncthreads();
    {
      int g0 = tid >> 5, w = tid & 31;
#pragma unroll
      for (int gi = 0; gi < 4; ++gi) {
        int g = gi * 8 + g0;
        union { short8 s; __hip_bfloat16 hv[8]; } pk;
#pragma unroll
        for (int cc = 0; cc < 8; ++cc)
          pk.hv[cc] = __float2bfloat16(tile[(g * 8 + cc) * 33 + w]);
        *(short8*)(xTB + ((((b * 32 + g) * 34 + h + 1) * 34) + (w + 1)) * 16) = pk.s;
      }
    }
    if (h < 2) {  // h==0 -> row 0 + col 0 ; h==1 -> row 33 + col 33 (all g)
      uint4 z4 = {0u, 0u, 0u, 0u};
      int edge = h * 33;
      for (int i = tid; i < 32 * 34; i += 256) {
        int g = i / 34, w = i - g * 34;
        *(uint4*)(xTB + ((((b * 32 + g) * 34 + edge) * 34) + w) * 16) = z4;
      }
      for (int i = tid; i < 32 * 32; i += 256) {
        int g = i >> 5, hh = 1 + (i & 31);
        *(uint4*)(xTB + ((((b * 32 + g) * 34 + hh) * 34) + edge) * 16) = z4;
      }
    }
    return;
  }

  // ---------------- build_w (register butterfly, ownership transposes) ----
  int wblk = blk - 512;
  if (wblk == 144) {
    if (tid < 256) {
      float a = 0.f;
#pragma unroll
      for (int s = 0; s < 9; ++s) a += bias[s * 256 + tid];
      biasout[tid] = a * (1.f / 9.f);
    }
    return;
  }
  float* mat = (float*)smem;              // 16 cols x 272 floats = 17408 B
  float* tws = (float*)(smem + 17408);    // 2*255*4 floats = 8160 B
  int sidx = wblk >> 4;
  int colbase = (wblk & 15) * 16;

  for (int i = tid; i < 255 * 4; i += 256) {
    tws[i]           = tw1[sidx * 255 * 4 + i];
    tws[255 * 4 + i] = tw2[sidx * 255 * 4 + i];
  }
  __syncthreads();                        // barrier 1 (tws ready)

  int c  = tid >> 4;                      // column within group (0..15)
  int rg = tid & 15;                      // row residue / row-group
  int cg = colbase + c;                   // global column

  float xs[16];

#pragma unroll
  for (int j = 0; j < 16; ++j) xs[j] = (j * 16 + rg == cg) ? 1.f : 0.f;

#define SSTAGE_S(PH, ST, M)                                                   \
  {                                                                           \
    _Pragma("unroll")                                                         \
    for (int jb = 0; jb < 16; jb += 2 * (M)) {                                \
      _Pragma("unroll")                                                       \
      for (int q = 0; q < (M); ++q) {                                         \
        float4 tv = *(const float4*)&tws[((PH)*255 + (ST)-1 + q*16 + rg) * 4];\
        float x0 = xs[jb + q], x1 = xs[jb + q + (M)];                         \
        xs[jb + q]       = tv.x * x0 + tv.y * x1;                             \
        xs[jb + q + (M)] = tv.z * x0 + tv.w * x1;                             \
      }                                                                       \
    }                                                                         \
  }

#define RSTAGE(PH, ST)                                                        \
  {                                                                           \
    _Pragma("unroll")                                                         \
    for (int base = 0; base < 16; base += 2 * (ST)) {                         \
      _Pragma("unroll")                                                       \
      for (int q = 0; q < (ST); ++q) {                                        \
        float4 tv = *(const float4*)&tws[((PH) * 255 + (ST) - 1 + q) * 4];    \
        float x0 = xs[base + q], x1 = xs[base + q + (ST)];                    \
        xs[base + q]        = tv.x * x0 + tv.y * x1;                          \
        xs[base + q + (ST)] = tv.z * x0 + tv.w * x1;                          \
      }                                                                       \
    }                                                                         \
  }

  SSTAGE_S(0, 128, 8) SSTAGE_S(0, 64, 4) SSTAGE_S(0, 32, 2) SSTAGE_S(0, 16, 1)

  {
    float* mc = mat + c * 272;
#pragma unroll
    for (int j = 0; j < 16; ++j) mc[j * 17 + rg] = xs[j];
  }
  __syncthreads();                        // barrier 2
  {
    float* mc = mat + c * 272;
#pragma unroll
    for (int j = 0; j < 16; ++j) xs[j] = mc[rg * 17 + j];
  }

  RSTAGE(0, 8) RSTAGE(0, 4) RSTAGE(0, 2) RSTAGE(0, 1)
  RSTAGE(1, 1) RSTAGE(1, 2) RSTAGE(1, 4) RSTAGE(1, 8)

  {
    float* mc = mat + c * 272;
#pragma unroll
    for (int j = 0; j < 16; ++j) mc[rg * 17 + j] = xs[j];
  }
  __syncthreads();                        // barrier 3
  {
    float* mc = mat + c * 272;
#pragma unroll
    for (int j = 0; j < 16; ++j) xs[j] = mc[j * 17 + rg];
  }

  SSTAGE_S(1, 16, 1) SSTAGE_S(1, 32, 2) SSTAGE_S(1, 64, 4) SSTAGE_S(1, 128, 8)

  {
    int pr = cg >> 6, g = (cg >> 3) & 7, c8 = cg & 7;
#pragma unroll
    for (int j = 0; j < 16; ++j) {
      int nq = j >> 2, nl = (j & 3) * 16 + rg;
      int o = ((((sidx * 4 + pr) * 4 + nq) * 8 + g) * 64 + nl) * 8 + c8;
      Wg[o] = __float2bfloat16(xs[j] * (1.f / 9.f));
    }
  }
#undef SSTAGE_S
#undef RSTAGE
}

// ---------------------------------------------------------------------------
// k_gemm R29: n-split + LDS-shared B, CO-RESIDENT version (R25 fixed).
// R25's regression diagnosed: grid 256 = 1 block/CU -> every stage barrier
// stalled the whole CU (nothing co-resident to overlap staging). Fix: split
// each 8-wave block into TWO 4-wave blocks (nh = n-half), grid 512 -> 2
// blocks/CU; one block computes while the other stages. Arithmetic: per CU,
// A = 1152 VMEM wave-instr (~8.6 µs, TA port) || 2304 ds_read_b128
// (~11.5 µs, LDS port) || MFMA 1.9 µs/SIMD -> floor ~12 µs, and the k-split
// reduction epilogue VANISHES (full-K in-wave, direct stores).
// Math/addressing identical to R25 (passed, absmax 0.03125): K order =
// stage x (si,sj) x octet-pair; half-wave g-slab offset 2176 B = 0 mod 32
// banks -> 2-way aliasing only (free). XCD swizzle kept.
// ---------------------------------------------------------------------------
__global__ __launch_bounds__(256, 2) void k_gemm(const __hip_bfloat16* __restrict__ xTg,
                                                 const __hip_bfloat16* __restrict__ Wg,
                                                 const float* __restrict__ biasout,
                                                 float* __restrict__ out) {
  __shared__ __align__(128) char lds[34816];   // [16 g][4 r][34 col][16 B]
  const char* WgB = (const char*)Wg;
  const char* xTB = (const char*)xTg;

  // XCD swizzle: xcd = blk&7 owns b in {2*xcd, 2*xcd+1}. Grid 512.
  int blk  = blockIdx.x;
  int rest = blk >> 3;              // 0..63
  int b    = 2 * (blk & 7) + (rest >> 5);
  int r2   = rest & 31;
  int pt   = r2 >> 1;               // 0..15
  int nh   = r2 & 1;                // n-half (0: n 0..127, 1: n 128..255)
  int h0   = pt * 2;                // output rows h0, h0+1

  int tid  = threadIdx.x;
  int lane = tid & 63;
  int w    = tid >> 6;              // wave 0..3
  int half = lane >> 5;
  int l31  = lane & 31;

  int w8   = nh * 4 + w;            // virtual wave 0..7 (R25 mapping)
  int nq   = w8 >> 1;               // n-quad 0..3
  int noff = (w8 & 1) * 32;         // 32-n offset within quad

  float16v acc[2];                  // pix-row tiles p2 = 0,1 (32 regs)
#pragma unroll
  for (int p2 = 0; p2 < 2; ++p2)
#pragma unroll
    for (int e = 0; e < 16; ++e) acc[p2][e] = 0.f;

  // A per-lane base: Wg[(s*4+pr)*4+nq][g8][n = noff+l31][c-octet 16B].
  const char* pA = WgB + nq * 8192 + (noff + l31) * 16;

#pragma unroll 1
  for (int st = 0; st < 2; ++st) {
    __syncthreads();                // previous stage's reads complete
    // Stage B window: global g = st*16 + g, rows h0..h0+3, cols 0..33.
    for (int c = tid; c < 2176; c += 256) {
      int g   = c / 136;            // 136 = 4*34
      int rem = c - g * 136;
      int r   = rem / 34;
      int col = rem - r * 34;
      short8 v = *(const short8*)(xTB + (b * 32 + st * 16 + g) * 18496 +
                                  (h0 + r) * 544 + col * 16);
      *(short8*)(lds + c * 16) = v;
    }
    __syncthreads();
    // Compute: 9 shifts x 8 octet-pairs of this stage.
#pragma unroll
    for (int si = 0; si < 3; ++si) {
#pragma unroll
      for (int sj = 0; sj < 3; ++sj) {
#pragma unroll
        for (int t = 0; t < 8; ++t) {
          // A: octet o = 2t+half of stage; pr = st*2 + (t>>2); g8 = (2t+half)&7.
          const short8 a = *(const short8*)(pA +
              (si * 3 + sj) * 131072 + (st * 2 + (t >> 2)) * 32768 +
              ((2 * t + half) & 7) * 1024);
          // B from LDS: g = 2t+half, row = si+p2, col = sj+l31.
          const char* bb = lds + (((2 * t + half) * 4 + si) * 34 + sj + l31) * 16;
          short8 b0 = *(const short8*)(bb);
          short8 b1 = *(const short8*)(bb + 544);     // +1 row
          acc[0] = __builtin_amdgcn_mfma_f32_32x32x16_bf16(a, b0, acc[0], 0, 0, 0);
          acc[1] = __builtin_amdgcn_mfma_f32_32x32x16_bf16(a, b1, acc[1], 0, 0, 0);
        }
      }
    }
  }

  // Direct store (no reduction). D layout: col=l31 (pix w), row -> n.
#pragma unroll
  for (int reg = 0; reg < 16; ++reg) {
    int n = nh * 128 + w * 32 + (reg & 3) + 8 * (reg >> 2) + 4 * half;
    float bv = biasout[n];
    float* o0 = &out[((b * 256 + n) * 32 + h0) * 32 + l31];
    o0[0]  = acc[0][reg] + bv;
    o0[32] = acc[1][reg] + bv;      // row h0+1
  }
}

// ---------------------------------------------------------------------------
extern "C" void kernel_launch(void* const* d_in, const int* in_sizes, int n_in,
                              void* d_out, int out_size, void* d_ws, size_t ws_size,
                              hipStream_t stream) {
  const float* x    = (const float*)d_in[0];
  const float* tw1  = (const float*)d_in[1];
  const float* tw2  = (const float*)d_in[2];
  const float* bias = (const float*)d_in[3];
  float* out = (float*)d_out;

  char* ws = (char*)d_ws;
  __hip_bfloat16* xTg = (__hip_bfloat16*)ws;
  __hip_bfloat16* Wg  = (__hip_bfloat16*)(ws + XT_BYTES);
  float* biasout      = (float*)(ws + XT_BYTES + WG_BYTES);

  k_prep<<<657, 256, 0, stream>>>(x, tw1, tw2, bias, xTg, Wg, biasout);
  k_gemm<<<512, 256, 0, stream>>>(xTg, Wg, biasout, out);
}

// Round 18
// 102.202 us; speedup vs baseline: 1.1107x; 1.1107x over previous
//
#include <hip/hip_runtime.h>
#include <hip/hip_bf16.h>

typedef __attribute__((ext_vector_type(8))) short short8;
typedef __attribute__((ext_vector_type(4))) float float4v;
typedef __attribute__((ext_vector_type(16))) float float16v;

// Workspace layout (bytes):
//   xTg  bf16 [16 b][32 g][34 h][34 w][8 c]             : 9,469,952
//   Wg   bf16 [9 s][4 pair][4 nq][8 g][64 n][8 c]       : 1,179,648
//   biasout f32 [256]                                   : 1,024
#define XT_BYTES (16*32*34*34*8*2)
#define WG_BYTES (9*4*4*8*64*8*2)

// ---------------------------------------------------------------------------
// k_prep = R28 (session best): transpose + conflict-free register-butterfly
// build_w (strided/consecutive ownership swap via two padded LDS transposes;
// 4 barriers, zero shuffles, zero bank conflicts).
// ---------------------------------------------------------------------------
__global__ __launch_bounds__(256) void k_prep(const float* __restrict__ x,
                                              const float* __restrict__ tw1,
                                              const float* __restrict__ tw2,
                                              const float* __restrict__ bias,
                                              __hip_bfloat16* __restrict__ xTg,
                                              __hip_bfloat16* __restrict__ Wg,
                                              float* __restrict__ biasout) {
  __shared__ __align__(16) char smem[256 * 33 * 4];   // 33792 B
  int blk = blockIdx.x;
  int tid = threadIdx.x;

  if (blk < 512) {   // ---------------- transpose ----------------
    float* tile = (float*)smem;
    char* xTB = (char*)xTg;
    int h = blk & 31, b = blk >> 5;
    {
      int w4 = (tid & 7) * 4, c0 = tid >> 3;
#pragma unroll
      for (int j = 0; j < 8; ++j) {
        int ci = c0 + 32 * j;
        float4 v = *(const float4*)&x[((b * 256 + ci) * 32 + h) * 32 + w4];
        *(float4*)&tile[ci * 33 + w4] = v;
      }
    }
    __syncthreads();
    {
      int g0 = tid >> 5, w = tid & 31;
#pragma unroll
      for (int gi = 0; gi < 4; ++gi) {
        int g = gi * 8 + g0;
        union { short8 s; __hip_bfloat16 hv[8]; } pk;
#pragma unroll
        for (int cc = 0; cc < 8; ++cc)
          pk.hv[cc] = __float2bfloat16(tile[(g * 8 + cc) * 33 + w]);
        *(short8*)(xTB + ((((b * 32 + g) * 34 + h + 1) * 34) + (w + 1)) * 16) = pk.s;
      }
    }
    if (h < 2) {  // h==0 -> row 0 + col 0 ; h==1 -> row 33 + col 33 (all g)
      uint4 z4 = {0u, 0u, 0u, 0u};
      int edge = h * 33;
      for (int i = tid; i < 32 * 34; i += 256) {
        int g = i / 34, w = i - g * 34;
        *(uint4*)(xTB + ((((b * 32 + g) * 34 + edge) * 34) + w) * 16) = z4;
      }
      for (int i = tid; i < 32 * 32; i += 256) {
        int g = i >> 5, hh = 1 + (i & 31);
        *(uint4*)(xTB + ((((b * 32 + g) * 34 + hh) * 34) + edge) * 16) = z4;
      }
    }
    return;
  }

  // ---------------- build_w (register butterfly, ownership transposes) ----
  int wblk = blk - 512;
  if (wblk == 144) {
    if (tid < 256) {
      float a = 0.f;
#pragma unroll
      for (int s = 0; s < 9; ++s) a += bias[s * 256 + tid];
      biasout[tid] = a * (1.f / 9.f);
    }
    return;
  }
  float* mat = (float*)smem;              // 16 cols x 272 floats = 17408 B
  float* tws = (float*)(smem + 17408);    // 2*255*4 floats = 8160 B
  int sidx = wblk >> 4;
  int colbase = (wblk & 15) * 16;

  for (int i = tid; i < 255 * 4; i += 256) {
    tws[i]           = tw1[sidx * 255 * 4 + i];
    tws[255 * 4 + i] = tw2[sidx * 255 * 4 + i];
  }
  __syncthreads();                        // barrier 1 (tws ready)

  int c  = tid >> 4;                      // column within group (0..15)
  int rg = tid & 15;                      // row residue / row-group
  int cg = colbase + c;                   // global column

  float xs[16];

#pragma unroll
  for (int j = 0; j < 16; ++j) xs[j] = (j * 16 + rg == cg) ? 1.f : 0.f;

#define SSTAGE_S(PH, ST, M)                                                   \
  {                                                                           \
    _Pragma("unroll")                                                         \
    for (int jb = 0; jb < 16; jb += 2 * (M)) {                                \
      _Pragma("unroll")                                                       \
      for (int q = 0; q < (M); ++q) {                                         \
        float4 tv = *(const float4*)&tws[((PH)*255 + (ST)-1 + q*16 + rg) * 4];\
        float x0 = xs[jb + q], x1 = xs[jb + q + (M)];                         \
        xs[jb + q]       = tv.x * x0 + tv.y * x1;                             \
        xs[jb + q + (M)] = tv.z * x0 + tv.w * x1;                             \
      }                                                                       \
    }                                                                         \
  }

#define RSTAGE(PH, ST)                                                        \
  {                                                                           \
    _Pragma("unroll")                                                         \
    for (int base = 0; base < 16; base += 2 * (ST)) {                         \
      _Pragma("unroll")                                                       \
      for (int q = 0; q < (ST); ++q) {                                        \
        float4 tv = *(const float4*)&tws[((PH) * 255 + (ST) - 1 + q) * 4];    \
        float x0 = xs[base + q], x1 = xs[base + q + (ST)];                    \
        xs[base + q]        = tv.x * x0 + tv.y * x1;                          \
        xs[base + q + (ST)] = tv.z * x0 + tv.w * x1;                          \
      }                                                                       \
    }                                                                         \
  }

  SSTAGE_S(0, 128, 8) SSTAGE_S(0, 64, 4) SSTAGE_S(0, 32, 2) SSTAGE_S(0, 16, 1)

  {
    float* mc = mat + c * 272;
#pragma unroll
    for (int j = 0; j < 16; ++j) mc[j * 17 + rg] = xs[j];
  }
  __syncthreads();                        // barrier 2
  {
    float* mc = mat + c * 272;
#pragma unroll
    for (int j = 0; j < 16; ++j) xs[j] = mc[rg * 17 + j];
  }

  RSTAGE(0, 8) RSTAGE(0, 4) RSTAGE(0, 2) RSTAGE(0, 1)
  RSTAGE(1, 1) RSTAGE(1, 2) RSTAGE(1, 4) RSTAGE(1, 8)

  {
    float* mc = mat + c * 272;
#pragma unroll
    for (int j = 0; j < 16; ++j) mc[rg * 17 + j] = xs[j];
  }
  __syncthreads();                        // barrier 3
  {
    float* mc = mat + c * 272;
#pragma unroll
    for (int j = 0; j < 16; ++j) xs[j] = mc[j * 17 + rg];
  }

  SSTAGE_S(1, 16, 1) SSTAGE_S(1, 32, 2) SSTAGE_S(1, 64, 4) SSTAGE_S(1, 128, 8)

  {
    int pr = cg >> 6, g = (cg >> 3) & 7, c8 = cg & 7;
#pragma unroll
    for (int j = 0; j < 16; ++j) {
      int nq = j >> 2, nl = (j & 3) * 16 + rg;
      int o = ((((sidx * 4 + pr) * 4 + nq) * 8 + g) * 64 + nl) * 8 + c8;
      Wg[o] = __float2bfloat16(xs[j] * (1.f / 9.f));
    }
  }
#undef SSTAGE_S
#undef RSTAGE
}

// ---------------------------------------------------------------------------
// k_gemm = R24 (session best): R21 loop (direct loads, acc[2][2], grid 1024,
// XCD swizzle) + 4-barrier parallel-store epilogue.
// Structure closed by evidence: loop = VMEM-instruction service-throughput
// floor at b128 max width (R13 1-deep pipe null, R23 6-deep pinned pipe
// null, R21 occupancy x2 null, R18 XCD null, R16/R25/R29 LDS-B regressions,
// R19 warm-reps flat). Direct-from-global + HW L1 reuse is the right
// structure for this shape.
// ---------------------------------------------------------------------------
__global__ __launch_bounds__(256, 4) void k_gemm(const __hip_bfloat16* __restrict__ xTg,
                                                 const __hip_bfloat16* __restrict__ Wg,
                                                 const float* __restrict__ biasout,
                                                 float* __restrict__ out) {
  __shared__ __align__(64) char lds[32768];
  const char* WgB = (const char*)Wg;
  const char* xTB = (const char*)xTg;

  // XCD swizzle: xcd = blk&7 owns b in {2*xcd, 2*xcd+1}. Grid 1024.
  int blk  = blockIdx.x;
  int rest = blk >> 3;              // 0..127
  int b    = 2 * (blk & 7) + (rest >> 6);
  int r2   = rest & 63;
  int nq   = r2 & 3;
  int pt   = r2 >> 2;               // 0..15
  int h0   = pt * 2;                // output rows h0, h0+1

  int tid  = threadIdx.x;
  int lane = tid & 63;
  int wk   = tid >> 6;              // wave = k-quarter 0..3
  int half = lane >> 5;
  int l31  = lane & 31;

  float16v acc[2][2];               // [mt][p2] -- 64 regs
#pragma unroll
  for (int mt = 0; mt < 2; ++mt)
#pragma unroll
    for (int p2 = 0; p2 < 2; ++p2)
#pragma unroll
      for (int e = 0; e < 16; ++e) acc[mt][p2][e] = 0.f;

  // A: within a slab, octet (2wk+half), rows mt*32+l31 (+512 B for mt=1).
  int aoff = ((2 * wk + half) * 64 + l31) * 16;
  // B: octet (2wk+half) of chan-pair p, padded row h0, col l31.
  int bbase = ((((b * 32 + 2 * wk + half) * 34 + h0) * 34) + l31) * 16;

#pragma unroll 2
  for (int p = 0; p < 4; ++p) {
    const char* Bp = xTB + bbase + p * (8 * 34 * 34) * 16;
    const char* Ap = WgB + (p * 4 + nq) * 8192;
#pragma unroll
    for (int si = 0; si < 3; ++si) {
#pragma unroll
      for (int sj = 0; sj < 3; ++sj) {
        const char* Aslab = Ap + (si * 3 + sj) * (16 * 8192);
        short8 a0 = *(const short8*)(Aslab + aoff);
        short8 a1 = *(const short8*)(Aslab + aoff + 32 * 16);
        const char* Bq = Bp + (si * 34 + sj) * 16;
        short8 b0 = *(const short8*)(Bq);
        short8 b1 = *(const short8*)(Bq + 34 * 16);
        acc[0][0] = __builtin_amdgcn_mfma_f32_32x32x16_bf16(a0, b0, acc[0][0], 0, 0, 0);
        acc[0][1] = __builtin_amdgcn_mfma_f32_32x32x16_bf16(a0, b1, acc[0][1], 0, 0, 0);
        acc[1][0] = __builtin_amdgcn_mfma_f32_32x32x16_bf16(a1, b0, acc[1][0], 0, 0, 0);
        acc[1][1] = __builtin_amdgcn_mfma_f32_32x32x16_bf16(a1, b1, acc[1][1], 0, 0, 0);
      }
    }
  }

  // Bias preload (latency hidden under the reduction barriers).
  float bv[16];
  if (wk < 2) {
#pragma unroll
    for (int reg = 0; reg < 16; ++reg)
      bv[reg] = biasout[nq * 64 + wk * 32 + (reg & 3) + 8 * (reg >> 2) + 4 * half];
  }

  // LDS helpers: slot*4096 + lane*16, 4 chunks @ +1024 (conflict-free b128).
  auto st16 = [&](int slot, const float16v& v) {
    char* base = lds + slot * 4096 + lane * 16;
    *(float4v*)(base)        = (float4v){v[0],  v[1],  v[2],  v[3]};
    *(float4v*)(base + 1024) = (float4v){v[4],  v[5],  v[6],  v[7]};
    *(float4v*)(base + 2048) = (float4v){v[8],  v[9],  v[10], v[11]};
    *(float4v*)(base + 3072) = (float4v){v[12], v[13], v[14], v[15]};
  };
  auto ld16add = [&](int slot, float16v& v) {
    const char* base = lds + slot * 4096 + lane * 16;
    float4v t0 = *(const float4v*)(base);
    float4v t1 = *(const float4v*)(base + 1024);
    float4v t2 = *(const float4v*)(base + 2048);
    float4v t3 = *(const float4v*)(base + 3072);
    v[0] += t0[0]; v[1] += t0[1]; v[2]  += t0[2]; v[3]  += t0[3];
    v[4] += t1[0]; v[5] += t1[1]; v[6]  += t1[2]; v[7]  += t1[3];
    v[8] += t2[0]; v[9] += t2[1]; v[10] += t2[2]; v[11] += t2[3];
    v[12] += t3[0]; v[13] += t3[1]; v[14] += t3[2]; v[15] += t3[3];
  };

  // Round 1: wk2 -> slots 0..3, wk3 -> slots 4..7; wk0 += wk2, wk1 += wk3.
  __syncthreads();
  if (wk == 2) { st16(0, acc[0][0]); st16(1, acc[0][1]); st16(2, acc[1][0]); st16(3, acc[1][1]); }
  if (wk == 3) { st16(4, acc[0][0]); st16(5, acc[0][1]); st16(6, acc[1][0]); st16(7, acc[1][1]); }
  __syncthreads();
  if (wk == 0) { ld16add(0, acc[0][0]); ld16add(1, acc[0][1]); ld16add(2, acc[1][0]); ld16add(3, acc[1][1]); }
  if (wk == 1) { ld16add(4, acc[0][0]); ld16add(5, acc[0][1]); ld16add(6, acc[1][0]); ld16add(7, acc[1][1]); }
  __syncthreads();
  // Round 2: cross-exchange by mt.
  if (wk == 1) { st16(0, acc[0][0]); st16(1, acc[0][1]); }
  if (wk == 0) { st16(4, acc[1][0]); st16(5, acc[1][1]); }
  __syncthreads();
  // Final: wk0 stores mt=0, wk1 stores mt=1, in parallel.
  if (wk == 0) {
    ld16add(0, acc[0][0]); ld16add(1, acc[0][1]);   // (w0+w2)+(w1+w3), mt0
#pragma unroll
    for (int reg = 0; reg < 16; ++reg) {
      int n = nq * 64 + (reg & 3) + 8 * (reg >> 2) + 4 * half;
      float* o0 = &out[((b * 256 + n) * 32 + h0) * 32 + l31];
      o0[0]  = acc[0][0][reg] + bv[reg];
      o0[32] = acc[0][1][reg] + bv[reg];
    }
  }
  if (wk == 1) {
    ld16add(4, acc[1][0]); ld16add(5, acc[1][1]);   // (w1+w3)+(w0+w2), mt1
#pragma unroll
    for (int reg = 0; reg < 16; ++reg) {
      int n = nq * 64 + 32 + (reg & 3) + 8 * (reg >> 2) + 4 * half;
      float* o0 = &out[((b * 256 + n) * 32 + h0) * 32 + l31];
      o0[0]  = acc[1][0][reg] + bv[reg];
      o0[32] = acc[1][1][reg] + bv[reg];
    }
  }
}

// ---------------------------------------------------------------------------
extern "C" void kernel_launch(void* const* d_in, const int* in_sizes, int n_in,
                              void* d_out, int out_size, void* d_ws, size_t ws_size,
                              hipStream_t stream) {
  const float* x    = (const float*)d_in[0];
  const float* tw1  = (const float*)d_in[1];
  const float* tw2  = (const float*)d_in[2];
  const float* bias = (const float*)d_in[3];
  float* out = (float*)d_out;

  char* ws = (char*)d_ws;
  __hip_bfloat16* xTg = (__hip_bfloat16*)ws;
  __hip_bfloat16* Wg  = (__hip_bfloat16*)(ws + XT_BYTES);
  float* biasout      = (float*)(ws + XT_BYTES + WG_BYTES);

  k_prep<<<657, 256, 0, stream>>>(x, tw1, tw2, bias, xTg, Wg, biasout);
  k_gemm<<<1024, 256, 0, stream>>>(xTg, Wg, biasout, out);
}